// Round 13
// baseline (8232.072 us; speedup 1.0000x reference)
//
#include <hip/hip_runtime.h>

#define SEQ   1024
#define TLEN  1024
#define NB_B  4
#define NTHR  512
#define SLICE 3072

// d_out float map (786,432 floats):
//  [0,229376)       transposed weights (prep_t), consumed during lstm
//  [229376,294912)  h0 ring slot0 [128 pairs][512]   (< stash start 295936)
//  [688128,753664)  h0 ring slot1                    (> stash end 686592)
//  [753664,770048)  flags: flag0[p] @ +p*64, flag1[p] @ +8192+p*64 (memset 0)
//  slices 96..223 @ offset [1024,1536): final-h stash
//  (mlp2_pre/mlp2_k later overwrite wt/flag areas -- stream-ordered after lstm)
#define WT0IH 0
#define WT0HH 32768
#define WT1IH 98304
#define WT1HH 163840
#define WTOT  229376
#define RING0 229376
#define RING1 688128
#define FLAGF 753664

__device__ __forceinline__ float sig1(float x) {
  return __builtin_amdgcn_rcpf(1.0f + __expf(-x));
}
__device__ __forceinline__ float tanh1(float x) {
  return 2.0f * __builtin_amdgcn_rcpf(1.0f + __expf(-2.0f * x)) - 1.0f;
}

__device__ __forceinline__ void astoref(float* pp, float v) {
  __hip_atomic_store(pp, v, __ATOMIC_RELAXED, __HIP_MEMORY_SCOPE_AGENT);
}
__device__ __forceinline__ float aloadf(const float* pp) {
  return __hip_atomic_load(pp, __ATOMIC_RELAXED, __HIP_MEMORY_SCOPE_AGENT);
}
__device__ __forceinline__ void astoreu(unsigned* pp, unsigned v) {
  __hip_atomic_store(pp, v, __ATOMIC_RELAXED, __HIP_MEMORY_SCOPE_AGENT);
}
__device__ __forceinline__ unsigned aloadu(const unsigned* pp) {
  return __hip_atomic_load(pp, __ATOMIC_RELAXED, __HIP_MEMORY_SCOPE_AGENT);
}

// One-time weight transpose: [row][k] -> [k>>2][row][k&3], into d_out[0..WTOT)
extern "C" __global__ void __launch_bounds__(256)
prep_t(const float* __restrict__ Wih0, const float* __restrict__ Whh0,
       const float* __restrict__ Wih1, const float* __restrict__ Whh1,
       float* __restrict__ wt) {
  const int idx = blockIdx.x * 256 + threadIdx.x;
  if (idx >= WTOT) return;
  float v; int r, k, base;
  if (idx < 32768)      { r = idx >> 6;  k = idx & 63;                  v = Wih0[idx]; base = WT0IH; }
  else if (idx < 98304) { int j = idx - 32768;  r = j >> 7; k = j & 127; v = Whh0[j];  base = WT0HH; }
  else if (idx < 163840){ int j = idx - 98304;  r = j >> 7; k = j & 127; v = Wih1[j];  base = WT1IH; }
  else                  { int j = idx - 163840; r = j >> 7; k = j & 127; v = Whh1[j];  base = WT1HH; }
  wt[base + (((k >> 2) * 512 + r) << 2) + (k & 3)] = v;
}

// Paired pipeline (r12-proven): blocks 0..127 = layer0 for batches 4p..4p+3,
// blocks 128..255 = layer1 same batches one step behind. Cross-block traffic:
// 512-float h0 publish + 2 flags per pair per step. This round: seamless
// weight streams, 2-3 syncs/step, register-prefetched X, rcpf activations.
extern "C" __global__ void __launch_bounds__(NTHR)
lstm_pair(const float* __restrict__ X1, const float* __restrict__ X2,
          const float* __restrict__ W1m, const float* __restrict__ b1m,
          const float* __restrict__ bih0, const float* __restrict__ bhh0,
          const float* __restrict__ bih1, const float* __restrict__ bhh1,
          const float* wt, float* out) {
  __shared__ float hbuf[NB_B * 320];   // per batch: feat[64] | h0[128] | h1[128]
  __shared__ float gacc[512 * NB_B];   // [gate-row][batch]

  const int tid = threadIdx.x;
  const int bid = blockIdx.x;
  const bool L1role = bid >= 128;
  const int p  = L1role ? bid - 128 : bid;
  const int r  = tid;                  // gate row 0..511
  const int u  = tid & 127;            // hidden unit
  const int bp = tid >> 7;             // batch slot 0..3

  unsigned* flag0 = (unsigned*)(out + FLAGF) + p * 64;
  unsigned* flag1 = (unsigned*)(out + FLAGF) + 8192 + p * 64;

  for (int i = tid; i < NB_B * 320; i += NTHR) hbuf[i] = 0.0f;
  __syncthreads();

  if (!L1role) {
    // ---------------- layer-0 producer ----------------
    const int m  = tid & 63;           // mlp1 unit
    const int bf = tid >> 6;           // mlp1 batch slot (active if < NB_B)
    float w1r[5];
    float b1r = 0.0f;
    const float* xptr = X1;            // per-batch x base (bf < NB_B only)
    if (bf < NB_B) {
      #pragma unroll
      for (int i = 0; i < 5; ++i) w1r[i] = W1m[m * 5 + i];
      b1r = b1m[m];
      const int ebx = p * NB_B + bf;
      xptr = (ebx < 256) ? (X1 + (size_t)ebx * SEQ * 5)
                         : (X2 + (size_t)(ebx - 256) * SEQ * 5);
    }
    const float bias0 = bih0[r] + bhh0[r];
    const float4* w0s = (const float4*)wt + r;   // seamless 48-kc stream (Wih0||Whh0)

    // prologue: feat[0]
    if (bf < NB_B) {
      const float* x = xptr;           // t = 0
      float s = b1r;
      #pragma unroll
      for (int i = 0; i < 5; ++i) s = fmaf(w1r[i], x[i], s);
      hbuf[bf * 320 + m] = fmaxf(s, 0.0f);
    }
    __syncthreads();

    float c0 = 0.0f;
    for (int t = 0; t < SEQ; ++t) {
      // slot t&1 reuse guard: L1 must have consumed h0[t-2] (checked early, big slack)
      if (tid == 0 && t >= 2) {
        while (aloadu(flag1) < (unsigned)(t - 1)) __builtin_amdgcn_s_sleep(2);
      }
      // prefetch x[t+1] into registers (consumed after gates)
      float xr0 = 0.f, xr1 = 0.f, xr2 = 0.f, xr3 = 0.f, xr4 = 0.f;
      if (bf < NB_B) {
        const int tp1 = (t + 1 < SEQ) ? t + 1 : SEQ - 1;
        const float* x = xptr + (size_t)tp1 * 5;
        xr0 = x[0]; xr1 = x[1]; xr2 = x[2]; xr3 = x[3]; xr4 = x[4];
      }

      // gates: one seamless 48-kc stream over [feat|h0]
      {
        float a0 = bias0, a1 = bias0, a2 = bias0, a3 = bias0;
        #pragma unroll 8
        for (int kc = 0; kc < 48; ++kc) {
          float4 wv = w0s[kc * 512];
          float4 h0 = *(const float4*)&hbuf[0 * 320 + kc * 4];
          float4 h1 = *(const float4*)&hbuf[1 * 320 + kc * 4];
          float4 h2 = *(const float4*)&hbuf[2 * 320 + kc * 4];
          float4 h3 = *(const float4*)&hbuf[3 * 320 + kc * 4];
          a0 = fmaf(wv.x, h0.x, fmaf(wv.y, h0.y, fmaf(wv.z, h0.z, fmaf(wv.w, h0.w, a0))));
          a1 = fmaf(wv.x, h1.x, fmaf(wv.y, h1.y, fmaf(wv.z, h1.z, fmaf(wv.w, h1.w, a1))));
          a2 = fmaf(wv.x, h2.x, fmaf(wv.y, h2.y, fmaf(wv.z, h2.z, fmaf(wv.w, h2.w, a2))));
          a3 = fmaf(wv.x, h3.x, fmaf(wv.y, h3.y, fmaf(wv.z, h3.z, fmaf(wv.w, h3.w, a3))));
        }
        *(float4*)&gacc[r * NB_B] = make_float4(a0, a1, a2, a3);
      }
      __syncthreads();                 // gacc ready; all hbuf reads done

      // update -> h0[t] (local + ring) ; feat[t+1]
      {
        float gi = gacc[(u)       * NB_B + bp];
        float gf = gacc[(128 + u) * NB_B + bp];
        float gg = gacc[(256 + u) * NB_B + bp];
        float go = gacc[(384 + u) * NB_B + bp];
        float cc = sig1(gf) * c0 + sig1(gi) * tanh1(gg);
        c0 = cc;
        float hv = sig1(go) * tanh1(cc);
        hbuf[bp * 320 + 64 + u] = hv;
        float* rg = out + ((t & 1) ? RING1 : RING0) + p * 512;
        astoref(&rg[tid], hv);
      }
      if (bf < NB_B) {
        float s = b1r;
        s = fmaf(w1r[0], xr0, s); s = fmaf(w1r[1], xr1, s); s = fmaf(w1r[2], xr2, s);
        s = fmaf(w1r[3], xr3, s); s = fmaf(w1r[4], xr4, s);
        hbuf[bf * 320 + m] = fmaxf(s, 0.0f);
      }
      __syncthreads();                 // ring stores drained (vmcnt0) + hbuf ready
      if (tid == 0) astoreu(flag0, (unsigned)(t + 1));
    }
  } else {
    // ---------------- layer-1 consumer ----------------
    const float bias1 = bih1[r] + bhh1[r];
    const float4* w1s = (const float4*)(wt + WT1IH) + r;  // seamless 64-kc stream

    float c1 = 0.0f;
    for (int s = 0; s < SEQ; ++s) {
      if (tid == 0) {
        while (aloadu(flag0) < (unsigned)(s + 1)) __builtin_amdgcn_s_sleep(2);
      }
      __syncthreads();                 // flag confirmed; prev update writes ordered

      // stage h0[s]: one coalesced aload per thread -> LDS
      const float* rg = out + ((s & 1) ? RING1 : RING0) + p * 512;
      hbuf[bp * 320 + 64 + u] = aloadf(&rg[tid]);
      __syncthreads();                 // stage complete
      if (tid == 0) astoreu(flag1, (unsigned)(s + 1));   // slot consumed

      // gates: one seamless 64-kc stream over [h0|h1]
      {
        float a0 = bias1, a1 = bias1, a2 = bias1, a3 = bias1;
        #pragma unroll 8
        for (int kc = 0; kc < 64; ++kc) {
          float4 wv = w1s[kc * 512];
          float4 h0 = *(const float4*)&hbuf[0 * 320 + 64 + kc * 4];
          float4 h1 = *(const float4*)&hbuf[1 * 320 + 64 + kc * 4];
          float4 h2 = *(const float4*)&hbuf[2 * 320 + 64 + kc * 4];
          float4 h3 = *(const float4*)&hbuf[3 * 320 + 64 + kc * 4];
          a0 = fmaf(wv.x, h0.x, fmaf(wv.y, h0.y, fmaf(wv.z, h0.z, fmaf(wv.w, h0.w, a0))));
          a1 = fmaf(wv.x, h1.x, fmaf(wv.y, h1.y, fmaf(wv.z, h1.z, fmaf(wv.w, h1.w, a1))));
          a2 = fmaf(wv.x, h2.x, fmaf(wv.y, h2.y, fmaf(wv.z, h2.z, fmaf(wv.w, h2.w, a2))));
          a3 = fmaf(wv.x, h3.x, fmaf(wv.y, h3.y, fmaf(wv.z, h3.z, fmaf(wv.w, h3.w, a3))));
        }
        *(float4*)&gacc[r * NB_B] = make_float4(a0, a1, a2, a3);
      }
      __syncthreads();                 // gacc ready; hbuf reads done

      // update -> h1[s]; final stash. (next top-of-loop sync orders these writes)
      {
        float gi = gacc[(u)       * NB_B + bp];
        float gf = gacc[(128 + u) * NB_B + bp];
        float gg = gacc[(256 + u) * NB_B + bp];
        float go = gacc[(384 + u) * NB_B + bp];
        float cc = sig1(gf) * c1 + sig1(gi) * tanh1(gg);
        c1 = cc;
        float hvv = sig1(go) * tanh1(cc);
        hbuf[bp * 320 + 192 + u] = hvv;
        if (s == SEQ - 1)
          out[(size_t)(96 + p) * SLICE + 1024 + bp * 128 + u] = hvv;
      }
    }
  }
}

// base[b][m] = b1[m] + W1[m,0:128].hL[b] + W1[m,128:256].hR[b] -> out[b*SLICE + m]
extern "C" __global__ void __launch_bounds__(128)
mlp2_pre(const float* __restrict__ W1, const float* __restrict__ b1, float* out) {
  __shared__ float inpS[256];
  const int b = blockIdx.x, tid = threadIdx.x;
  inpS[tid]       = out[(size_t)(96  + (b >> 2)) * SLICE + 1024 + (b & 3) * 128 + tid];
  inpS[128 + tid] = out[(size_t)(160 + (b >> 2)) * SLICE + 1024 + (b & 3) * 128 + tid];
  __syncthreads();
  const float* wr = W1 + (size_t)tid * 257;
  float s = b1[tid];
  #pragma unroll 4
  for (int k = 0; k < 256; ++k) s = fmaf(wr[k], inpS[k], s);
  out[(size_t)b * SLICE + tid] = s;
}

// out[b][t][o] = b2[o] + sum_m W2[o][m] * relu(base[b][m] + W1[m][256]*T[b][t])
extern "C" __global__ void __launch_bounds__(256)
mlp2_k(const float* __restrict__ T, const float* __restrict__ W1,
       const float* __restrict__ b2, const float* __restrict__ W2, float* out) {
  __shared__ float baseS[128], w1l[128], w2S[384];
  const int b = blockIdx.x, tid = threadIdx.x;
  if (tid < 128) {
    baseS[tid] = out[(size_t)b * SLICE + tid];   // read own slice BEFORE any write
    w1l[tid]   = W1[(size_t)tid * 257 + 256];
  }
  w2S[tid] = W2[tid];                            // 256 threads fill all 384
  if (tid < 128) w2S[256 + tid] = W2[256 + tid];
  __syncthreads();
  float x[4];
  #pragma unroll
  for (int q = 0; q < 4; ++q) x[q] = T[(size_t)b * TLEN + tid + q * 256];
  float a0[4], a1[4], a2[4];
  #pragma unroll
  for (int q = 0; q < 4; ++q) { a0[q] = b2[0]; a1[q] = b2[1]; a2[q] = b2[2]; }
  for (int mm = 0; mm < 128; ++mm) {
    float bm = baseS[mm], wl = w1l[mm];
    float w20 = w2S[mm], w21 = w2S[128 + mm], w22 = w2S[256 + mm];
    #pragma unroll
    for (int q = 0; q < 4; ++q) {
      float hv = fmaxf(fmaf(wl, x[q], bm), 0.0f);
      a0[q] = fmaf(w20, hv, a0[q]);
      a1[q] = fmaf(w21, hv, a1[q]);
      a2[q] = fmaf(w22, hv, a2[q]);
    }
  }
  #pragma unroll
  for (int q = 0; q < 4; ++q) {
    float* o = out + ((size_t)b * TLEN + tid + q * 256) * 3;
    o[0] = a0[q]; o[1] = a1[q]; o[2] = a2[q];
  }
}

extern "C" void kernel_launch(void* const* d_in, const int* in_sizes, int n_in,
                              void* d_out, int out_size, void* d_ws, size_t ws_size,
                              hipStream_t stream) {
  (void)in_sizes; (void)n_in; (void)out_size; (void)d_ws; (void)ws_size;
  const float* X1   = (const float*)d_in[0];
  const float* X2   = (const float*)d_in[1];
  const float* T    = (const float*)d_in[2];
  const float* W1m  = (const float*)d_in[3];
  const float* b1m  = (const float*)d_in[4];
  const float* Wih0 = (const float*)d_in[5];
  const float* Whh0 = (const float*)d_in[6];
  const float* bih0 = (const float*)d_in[7];
  const float* bhh0 = (const float*)d_in[8];
  const float* Wih1 = (const float*)d_in[9];
  const float* Whh1 = (const float*)d_in[10];
  const float* bih1 = (const float*)d_in[11];
  const float* bhh1 = (const float*)d_in[12];
  const float* W1p  = (const float*)d_in[13];
  const float* b1p  = (const float*)d_in[14];
  const float* W2p  = (const float*)d_in[15];
  const float* b2p  = (const float*)d_in[16];

  float* out = (float*)d_out;

  // flags must start at 0 every call
  hipMemsetAsync((char*)d_out + (size_t)FLAGF * 4, 0, 65536, stream);

  prep_t<<<dim3(896), dim3(256), 0, stream>>>(Wih0, Whh0, Wih1, Whh1, out);
  lstm_pair<<<dim3(256), dim3(NTHR), 0, stream>>>(X1, X2, W1m, b1m,
                                                  bih0, bhh0, bih1, bhh1, out, out);
  mlp2_pre<<<dim3(256), dim3(128), 0, stream>>>(W1p, b1p, out);
  mlp2_k<<<dim3(256), dim3(256), 0, stream>>>(T, W1p, b2p, W2p, out);
}

// Round 14
// 7899.916 us; speedup vs baseline: 1.0420x; 1.0420x over previous
//
#include <hip/hip_runtime.h>
#include <hip/hip_fp16.h>

#define SEQ   1024
#define TLEN  1024
#define NB_B  4
#define NTHR  512
#define SLICE 3072

// d_out float map (786,432 floats):
//  [0,114688)       fp16 transposed weights (229376 halves, prep_t), read during lstm
//  [229376,294912)  h0 ring slot0 [128 pairs][512]   (< stash start 295936)
//  [688128,753664)  h0 ring slot1                    (> stash end 686592)
//  [753664,770048)  flags: flag0[p] @ +p*64, flag1[p] @ +8192+p*64 (memset 0)
//  slices 96..223 @ offset [1024,1536): final-h stash
// Weight HALF-index offsets (within the half-array at d_out base):
#define WT0IH 0
#define WT0HH 32768
#define WT1IH 98304
#define WT1HH 163840
#define WTOT  229376
#define RING0 229376
#define RING1 688128
#define FLAGF 753664

__device__ __forceinline__ float sig1(float x)  { return 1.0f / (1.0f + __expf(-x)); }
__device__ __forceinline__ float tanh1(float x) { return 1.0f - 2.0f / (__expf(2.0f * x) + 1.0f); }

__device__ __forceinline__ void astoref(float* pp, float v) {
  __hip_atomic_store(pp, v, __ATOMIC_RELAXED, __HIP_MEMORY_SCOPE_AGENT);
}
__device__ __forceinline__ float aloadf(const float* pp) {
  return __hip_atomic_load(pp, __ATOMIC_RELAXED, __HIP_MEMORY_SCOPE_AGENT);
}
__device__ __forceinline__ void astoreu(unsigned* pp, unsigned v) {
  __hip_atomic_store(pp, v, __ATOMIC_RELAXED, __HIP_MEMORY_SCOPE_AGENT);
}
__device__ __forceinline__ unsigned aloadu(const unsigned* pp) {
  return __hip_atomic_load(pp, __ATOMIC_RELAXED, __HIP_MEMORY_SCOPE_AGENT);
}

// One-time weight transpose+cast: [row][k] fp32 -> fp16 [k>>2][row][k&3] in d_out
extern "C" __global__ void __launch_bounds__(256)
prep_t(const float* __restrict__ Wih0, const float* __restrict__ Whh0,
       const float* __restrict__ Wih1, const float* __restrict__ Whh1,
       __half* __restrict__ wt16) {
  const int idx = blockIdx.x * 256 + threadIdx.x;
  if (idx >= WTOT) return;
  float v; int r, k, base;
  if (idx < 32768)      { r = idx >> 6;  k = idx & 63;                  v = Wih0[idx]; base = WT0IH; }
  else if (idx < 98304) { int j = idx - 32768;  r = j >> 7; k = j & 127; v = Whh0[j];  base = WT0HH; }
  else if (idx < 163840){ int j = idx - 98304;  r = j >> 7; k = j & 127; v = Wih1[j];  base = WT1IH; }
  else                  { int j = idx - 163840; r = j >> 7; k = j & 127; v = Whh1[j];  base = WT1HH; }
  wt16[base + (((k >> 2) * 512 + r) << 2) + (k & 3)] = __float2half(v);
}

// fp16 weight quad -> two float2
#define WCVT(wp, wa, wb)                                                    \
  float2 wa = __half22float2(*reinterpret_cast<const __half2*>(&(wp).x));   \
  float2 wb = __half22float2(*reinterpret_cast<const __half2*>(&(wp).y));

// Paired pipeline (r12-proven, byte-identical structure; only weights are fp16):
// blocks 0..127 = layer0 for batches 4p..4p+3; blocks 128..255 = layer1 same
// batches one step behind. Cross-block: 512-float h0 publish + 2 flags/pair/step.
extern "C" __global__ void __launch_bounds__(NTHR)
lstm_pair(const float* __restrict__ X1, const float* __restrict__ X2,
          const float* __restrict__ W1m, const float* __restrict__ b1m,
          const float* __restrict__ bih0, const float* __restrict__ bhh0,
          const float* __restrict__ bih1, const float* __restrict__ bhh1,
          const float* wt, float* out) {
  __shared__ float hbuf[NB_B * 320];   // per batch: feat[64] | h0[128] | h1[128]
  __shared__ float gacc[512 * NB_B];   // [gate-row][batch]
  __shared__ float xS[NB_B * 5];

  const int tid = threadIdx.x;
  const int bid = blockIdx.x;
  const bool L1role = bid >= 128;
  const int p  = L1role ? bid - 128 : bid;
  const int r  = tid;                  // gate row 0..511
  const int u  = tid & 127;            // hidden unit
  const int bp = tid >> 7;             // batch slot 0..3

  const __half* wt16 = (const __half*)wt;
  unsigned* flag0 = (unsigned*)(out + FLAGF) + p * 64;
  unsigned* flag1 = (unsigned*)(out + FLAGF) + 8192 + p * 64;

  for (int i = tid; i < NB_B * 320; i += NTHR) hbuf[i] = 0.0f;
  __syncthreads();

  if (!L1role) {
    // ---------------- layer-0 producer ----------------
    const int m  = tid & 63;           // mlp1 unit
    const int bf = tid >> 6;           // mlp1 batch slot (active if < NB_B)
    float w1r[5];
    #pragma unroll
    for (int i = 0; i < 5; ++i) w1r[i] = W1m[m * 5 + i];
    const float b1r   = b1m[m];
    const float bias0 = bih0[r] + bhh0[r];

    const int b5 = (tid < NB_B * 5) ? tid / 5 : 0;
    const int c5 = tid - b5 * 5;
    const int ebx = p * NB_B + b5;
    const float* xsrc = (ebx < 256) ? (X1 + (size_t)ebx * SEQ * 5 + c5)
                                    : (X2 + (size_t)(ebx - 256) * SEQ * 5 + c5);

    const uint2* wih0 = (const uint2*)(wt16 + WT0IH) + r;  // [kc][512] half-quads
    const uint2* whh0 = (const uint2*)(wt16 + WT0HH) + r;

    float c0 = 0.0f;
    for (int t = 0; t < SEQ; ++t) {
      if (tid < NB_B * 5) xS[tid] = xsrc[(size_t)t * 5];
      __syncthreads();

      if (bf < NB_B) {                 // mlp1 feat
        const float* xb = &xS[bf * 5];
        float s = b1r;
        #pragma unroll
        for (int i = 0; i < 5; ++i) s = fmaf(w1r[i], xb[i], s);
        hbuf[bf * 320 + m] = fmaxf(s, 0.0f);
      }
      // ack-wait for ring slot t&1 (L1 must have staged h0[t-2]); overlaps feat
      if (tid == 0 && t >= 2) {
        while (aloadu(flag1) < (unsigned)(t - 1)) __builtin_amdgcn_s_sleep(2);
      }
      __syncthreads();

      {  // layer0 gate rows: Wih0.feat + Whh0.h0[t-1]
        float acc[NB_B];
        #pragma unroll
        for (int b = 0; b < NB_B; ++b) acc[b] = bias0;
        #pragma unroll 4
        for (int kc = 0; kc < 16; ++kc) {
          uint2 wp = wih0[kc * 512];
          WCVT(wp, wa, wb)
          #pragma unroll
          for (int b = 0; b < NB_B; ++b) {
            float4 hv = *(const float4*)&hbuf[b * 320 + kc * 4];
            acc[b] = fmaf(wa.x, hv.x, fmaf(wa.y, hv.y,
                     fmaf(wb.x, hv.z, fmaf(wb.y, hv.w, acc[b]))));
          }
        }
        #pragma unroll 4
        for (int kc = 0; kc < 32; ++kc) {
          uint2 wp = whh0[kc * 512];
          WCVT(wp, wa, wb)
          #pragma unroll
          for (int b = 0; b < NB_B; ++b) {
            float4 hv = *(const float4*)&hbuf[b * 320 + 64 + kc * 4];
            acc[b] = fmaf(wa.x, hv.x, fmaf(wa.y, hv.y,
                     fmaf(wb.x, hv.z, fmaf(wb.y, hv.w, acc[b]))));
          }
        }
        *(float4*)&gacc[r * NB_B] = make_float4(acc[0], acc[1], acc[2], acc[3]);
      }
      __syncthreads();

      float hv;
      {  // state update -> h0[t]
        float gi = gacc[(u)       * NB_B + bp];
        float gf = gacc[(128 + u) * NB_B + bp];
        float gg = gacc[(256 + u) * NB_B + bp];
        float go = gacc[(384 + u) * NB_B + bp];
        float cc = sig1(gf) * c0 + sig1(gi) * tanh1(gg);
        c0 = cc;
        hv = sig1(go) * tanh1(cc);
        hbuf[bp * 320 + 64 + u] = hv;
      }
      __syncthreads();

      // publish h0[t] (coalesced: idx = tid) then signal
      float* rg = out + ((t & 1) ? RING1 : RING0) + p * 512;
      astoref(&rg[tid], hv);
      __syncthreads();                 // all waves' stores drained (vmcnt0)
      if (tid == 0) astoreu(flag0, (unsigned)(t + 1));
    }
  } else {
    // ---------------- layer-1 consumer ----------------
    const float bias1 = bih1[r] + bhh1[r];
    const uint2* wih1 = (const uint2*)(wt16 + WT1IH) + r;
    const uint2* whh1 = (const uint2*)(wt16 + WT1HH) + r;

    float c1 = 0.0f;
    for (int s = 0; s < SEQ; ++s) {
      if (tid == 0) {
        while (aloadu(flag0) < (unsigned)(s + 1)) __builtin_amdgcn_s_sleep(2);
      }
      __syncthreads();

      // stage h0[s]: one coalesced aload per thread -> LDS
      const float* rg = out + ((s & 1) ? RING1 : RING0) + p * 512;
      hbuf[bp * 320 + 64 + u] = aloadf(&rg[tid]);
      __syncthreads();
      if (tid == 0) astoreu(flag1, (unsigned)(s + 1));   // slot consumed

      {  // layer1 gate rows: Wih1.h0[s] + Whh1.h1[s-1]
        float acc[NB_B];
        #pragma unroll
        for (int b = 0; b < NB_B; ++b) acc[b] = bias1;
        #pragma unroll 4
        for (int kc = 0; kc < 32; ++kc) {
          uint2 wp = wih1[kc * 512];
          WCVT(wp, wa, wb)
          #pragma unroll
          for (int b = 0; b < NB_B; ++b) {
            float4 hv = *(const float4*)&hbuf[b * 320 + 64 + kc * 4];
            acc[b] = fmaf(wa.x, hv.x, fmaf(wa.y, hv.y,
                     fmaf(wb.x, hv.z, fmaf(wb.y, hv.w, acc[b]))));
          }
        }
        #pragma unroll 4
        for (int kc = 0; kc < 32; ++kc) {
          uint2 wp = whh1[kc * 512];
          WCVT(wp, wa, wb)
          #pragma unroll
          for (int b = 0; b < NB_B; ++b) {
            float4 hv = *(const float4*)&hbuf[b * 320 + 192 + kc * 4];
            acc[b] = fmaf(wa.x, hv.x, fmaf(wa.y, hv.y,
                     fmaf(wb.x, hv.z, fmaf(wb.y, hv.w, acc[b]))));
          }
        }
        *(float4*)&gacc[r * NB_B] = make_float4(acc[0], acc[1], acc[2], acc[3]);
      }
      __syncthreads();

      {  // state update -> h1[s]; final stash
        float gi = gacc[(u)       * NB_B + bp];
        float gf = gacc[(128 + u) * NB_B + bp];
        float gg = gacc[(256 + u) * NB_B + bp];
        float go = gacc[(384 + u) * NB_B + bp];
        float cc = sig1(gf) * c1 + sig1(gi) * tanh1(gg);
        c1 = cc;
        float hvv = sig1(go) * tanh1(cc);
        hbuf[bp * 320 + 192 + u] = hvv;
        if (s == SEQ - 1)
          out[(size_t)(96 + p) * SLICE + 1024 + bp * 128 + u] = hvv;
      }
      __syncthreads();
    }
  }
}

// base[b][m] = b1[m] + W1[m,0:128].hL[b] + W1[m,128:256].hR[b] -> out[b*SLICE + m]
extern "C" __global__ void __launch_bounds__(128)
mlp2_pre(const float* __restrict__ W1, const float* __restrict__ b1, float* out) {
  __shared__ float inpS[256];
  const int b = blockIdx.x, tid = threadIdx.x;
  inpS[tid]       = out[(size_t)(96  + (b >> 2)) * SLICE + 1024 + (b & 3) * 128 + tid];
  inpS[128 + tid] = out[(size_t)(160 + (b >> 2)) * SLICE + 1024 + (b & 3) * 128 + tid];
  __syncthreads();
  const float* wr = W1 + (size_t)tid * 257;
  float s = b1[tid];
  #pragma unroll 4
  for (int k = 0; k < 256; ++k) s = fmaf(wr[k], inpS[k], s);
  out[(size_t)b * SLICE + tid] = s;
}

// out[b][t][o] = b2[o] + sum_m W2[o][m] * relu(base[b][m] + W1[m][256]*T[b][t])
extern "C" __global__ void __launch_bounds__(256)
mlp2_k(const float* __restrict__ T, const float* __restrict__ W1,
       const float* __restrict__ b2, const float* __restrict__ W2, float* out) {
  __shared__ float baseS[128], w1l[128], w2S[384];
  const int b = blockIdx.x, tid = threadIdx.x;
  if (tid < 128) {
    baseS[tid] = out[(size_t)b * SLICE + tid];   // read own slice BEFORE any write
    w1l[tid]   = W1[(size_t)tid * 257 + 256];
  }
  w2S[tid] = W2[tid];                            // 256 threads fill all 384
  if (tid < 128) w2S[256 + tid] = W2[256 + tid];
  __syncthreads();
  float x[4];
  #pragma unroll
  for (int q = 0; q < 4; ++q) x[q] = T[(size_t)b * TLEN + tid + q * 256];
  float a0[4], a1[4], a2[4];
  #pragma unroll
  for (int q = 0; q < 4; ++q) { a0[q] = b2[0]; a1[q] = b2[1]; a2[q] = b2[2]; }
  for (int mm = 0; mm < 128; ++mm) {
    float bm = baseS[mm], wl = w1l[mm];
    float w20 = w2S[mm], w21 = w2S[128 + mm], w22 = w2S[256 + mm];
    #pragma unroll
    for (int q = 0; q < 4; ++q) {
      float hv = fmaxf(fmaf(wl, x[q], bm), 0.0f);
      a0[q] = fmaf(w20, hv, a0[q]);
      a1[q] = fmaf(w21, hv, a1[q]);
      a2[q] = fmaf(w22, hv, a2[q]);
    }
  }
  #pragma unroll
  for (int q = 0; q < 4; ++q) {
    float* o = out + ((size_t)b * TLEN + tid + q * 256) * 3;
    o[0] = a0[q]; o[1] = a1[q]; o[2] = a2[q];
  }
}

extern "C" void kernel_launch(void* const* d_in, const int* in_sizes, int n_in,
                              void* d_out, int out_size, void* d_ws, size_t ws_size,
                              hipStream_t stream) {
  (void)in_sizes; (void)n_in; (void)out_size; (void)d_ws; (void)ws_size;
  const float* X1   = (const float*)d_in[0];
  const float* X2   = (const float*)d_in[1];
  const float* T    = (const float*)d_in[2];
  const float* W1m  = (const float*)d_in[3];
  const float* b1m  = (const float*)d_in[4];
  const float* Wih0 = (const float*)d_in[5];
  const float* Whh0 = (const float*)d_in[6];
  const float* bih0 = (const float*)d_in[7];
  const float* bhh0 = (const float*)d_in[8];
  const float* Wih1 = (const float*)d_in[9];
  const float* Whh1 = (const float*)d_in[10];
  const float* bih1 = (const float*)d_in[11];
  const float* bhh1 = (const float*)d_in[12];
  const float* W1p  = (const float*)d_in[13];
  const float* b1p  = (const float*)d_in[14];
  const float* W2p  = (const float*)d_in[15];
  const float* b2p  = (const float*)d_in[16];

  float* out = (float*)d_out;

  // flags must start at 0 every call
  hipMemsetAsync((char*)d_out + (size_t)FLAGF * 4, 0, 65536, stream);

  prep_t<<<dim3(896), dim3(256), 0, stream>>>(Wih0, Whh0, Wih1, Whh1, (__half*)out);
  lstm_pair<<<dim3(256), dim3(NTHR), 0, stream>>>(X1, X2, W1m, b1m,
                                                  bih0, bhh0, bih1, bhh1, out, out);
  mlp2_pre<<<dim3(256), dim3(128), 0, stream>>>(W1p, b1p, out);
  mlp2_k<<<dim3(256), dim3(256), 0, stream>>>(T, W1p, b2p, W2p, out);
}

// Round 15
// 7594.075 us; speedup vs baseline: 1.0840x; 1.0403x over previous
//
#include <hip/hip_runtime.h>
#include <hip/hip_fp16.h>

#define SEQ   1024
#define TLEN  1024
#define NB_B  4
#define NTHR  512
#define SLICE 3072

// d_out float map (786,432 floats):
//  [0,114688)       fp16 transposed weights (229376 halves, prep_t)
//  [114688,180224)  h0 ring slot0 [128 pairs][512]
//  [180224,245760)  h0 ring slot1
//  [688128,753664)  h0 ring slot2          (stash ends 686592; flags start 753664)
//  [753664,770048)  flags: flag0[p] @ +p*64, flagC[p] @ +8192+p*64 (memset 0)
//  slices 96..223 @ offset [1024,1536): final-h stash = floats [295936,686592)
// Weight HALF-index offsets (within half-array at d_out base):
#define WT0IH 0
#define WT0HH 32768
#define WT1IH 98304
#define WT1HH 163840
#define WTOT  229376
#define RINGA 114688
#define RINGB 180224
#define RINGC 688128
#define FLAGF 753664

__device__ __forceinline__ float sig1(float x)  { return 1.0f / (1.0f + __expf(-x)); }
__device__ __forceinline__ float tanh1(float x) { return 1.0f - 2.0f / (__expf(2.0f * x) + 1.0f); }

__device__ __forceinline__ void astoref(float* pp, float v) {
  __hip_atomic_store(pp, v, __ATOMIC_RELAXED, __HIP_MEMORY_SCOPE_AGENT);
}
__device__ __forceinline__ float aloadf(const float* pp) {
  return __hip_atomic_load(pp, __ATOMIC_RELAXED, __HIP_MEMORY_SCOPE_AGENT);
}
__device__ __forceinline__ void astoreu(unsigned* pp, unsigned v) {
  __hip_atomic_store(pp, v, __ATOMIC_RELAXED, __HIP_MEMORY_SCOPE_AGENT);
}
__device__ __forceinline__ unsigned aloadu(const unsigned* pp) {
  return __hip_atomic_load(pp, __ATOMIC_RELAXED, __HIP_MEMORY_SCOPE_AGENT);
}
__device__ __forceinline__ int rbase(int sl) {   // ring slot -> d_out float offset
  return (sl == 2) ? RINGC : (RINGA + sl * 65536);
}

// One-time weight transpose+cast: [row][k] fp32 -> fp16 [k>>2][row][k&3] in d_out
extern "C" __global__ void __launch_bounds__(256)
prep_t(const float* __restrict__ Wih0, const float* __restrict__ Whh0,
       const float* __restrict__ Wih1, const float* __restrict__ Whh1,
       __half* __restrict__ wt16) {
  const int idx = blockIdx.x * 256 + threadIdx.x;
  if (idx >= WTOT) return;
  float v; int r, k, base;
  if (idx < 32768)      { r = idx >> 6;  k = idx & 63;                  v = Wih0[idx]; base = WT0IH; }
  else if (idx < 98304) { int j = idx - 32768;  r = j >> 7; k = j & 127; v = Whh0[j];  base = WT0HH; }
  else if (idx < 163840){ int j = idx - 98304;  r = j >> 7; k = j & 127; v = Wih1[j];  base = WT1IH; }
  else                  { int j = idx - 163840; r = j >> 7; k = j & 127; v = Whh1[j];  base = WT1HH; }
  wt16[base + (((k >> 2) * 512 + r) << 2) + (k & 3)] = __float2half(v);
}

// fp16 weight quad -> two float2
#define WCVT(wp, wa, wb)                                                    \
  float2 wa = __half22float2(*reinterpret_cast<const __half2*>(&(wp).x));   \
  float2 wb = __half22float2(*reinterpret_cast<const __half2*>(&(wp).y));

// Paired pipeline, ring depth 3, register-prefetched h0, 2 syncs/step.
// blocks 0..127 = layer0 for batches 4p..4p+3; blocks 128..255 = layer1 same
// batches ~2 steps behind.
extern "C" __global__ void __launch_bounds__(NTHR)
lstm_pair(const float* __restrict__ X1, const float* __restrict__ X2,
          const float* __restrict__ W1m, const float* __restrict__ b1m,
          const float* __restrict__ bih0, const float* __restrict__ bhh0,
          const float* __restrict__ bih1, const float* __restrict__ bhh1,
          const float* wt, float* out) {
  __shared__ float hbuf[NB_B * 320];   // per batch: feat[64] | h0[128] | h1[128]
  __shared__ float gacc[512 * NB_B];   // [gate-row][batch]

  const int tid = threadIdx.x;
  const int bid = blockIdx.x;
  const bool L1role = bid >= 128;
  const int p  = L1role ? bid - 128 : bid;
  const int r  = tid;                  // gate row 0..511
  const int u  = tid & 127;            // hidden unit
  const int bp = tid >> 7;             // batch slot 0..3

  const __half* wt16 = (const __half*)wt;
  unsigned* flag0 = (unsigned*)(out + FLAGF) + p * 64;          // L0 progress
  unsigned* flagC = (unsigned*)(out + FLAGF) + 8192 + p * 64;   // L1 consumed

  for (int i = tid; i < NB_B * 320; i += NTHR) hbuf[i] = 0.0f;
  __syncthreads();

  if (!L1role) {
    // ---------------- layer-0 producer ----------------
    const int m  = tid & 63;           // mlp1 unit
    const int bf = tid >> 6;           // mlp1 batch slot (active if < NB_B)
    float w1r[5]; float b1r = 0.0f;
    const float* xptr = X1;
    if (bf < NB_B) {
      #pragma unroll
      for (int i = 0; i < 5; ++i) w1r[i] = W1m[m * 5 + i];
      b1r = b1m[m];
      const int ebx = p * NB_B + bf;
      xptr = (ebx < 256) ? (X1 + (size_t)ebx * SEQ * 5)
                         : (X2 + (size_t)(ebx - 256) * SEQ * 5);
    }
    const float bias0 = bih0[r] + bhh0[r];
    const uint2* wih0 = (const uint2*)(wt16 + WT0IH) + r;  // [kc][512] half-quads
    const uint2* whh0 = (const uint2*)(wt16 + WT0HH) + r;

    // prologue: feat[0]
    if (bf < NB_B) {
      float s = b1r;
      #pragma unroll
      for (int i = 0; i < 5; ++i) s = fmaf(w1r[i], xptr[i], s);
      hbuf[bf * 320 + m] = fmaxf(s, 0.0f);
    }
    __syncthreads();

    float c0 = 0.0f;
    int sl = 0;                        // slot(t)
    unsigned fcs = 0;                  // cached flagC (monotonic)
    for (int t = 0; t < SEQ; ++t) {
      // slot-reuse guard: L1 must have consumed h0[t-3] (tid0 only; the
      // post-gates sync orders every thread's ring store after this poll)
      if (tid == 0 && t >= 3) {
        const unsigned tgt = (unsigned)(t - 2);
        while (fcs < tgt) {
          fcs = aloadu(flagC);
          if (fcs < tgt) __builtin_amdgcn_s_sleep(2);
        }
      }

      {  // layer0 gate rows: Wih0.feat[t] + Whh0.h0[t-1]   (r14-proven loop)
        float acc[NB_B];
        #pragma unroll
        for (int b = 0; b < NB_B; ++b) acc[b] = bias0;
        #pragma unroll 4
        for (int kc = 0; kc < 16; ++kc) {
          uint2 wp = wih0[kc * 512];
          WCVT(wp, wa, wb)
          #pragma unroll
          for (int b = 0; b < NB_B; ++b) {
            float4 hv = *(const float4*)&hbuf[b * 320 + kc * 4];
            acc[b] = fmaf(wa.x, hv.x, fmaf(wa.y, hv.y,
                     fmaf(wb.x, hv.z, fmaf(wb.y, hv.w, acc[b]))));
          }
        }
        #pragma unroll 4
        for (int kc = 0; kc < 32; ++kc) {
          uint2 wp = whh0[kc * 512];
          WCVT(wp, wa, wb)
          #pragma unroll
          for (int b = 0; b < NB_B; ++b) {
            float4 hv = *(const float4*)&hbuf[b * 320 + 64 + kc * 4];
            acc[b] = fmaf(wa.x, hv.x, fmaf(wa.y, hv.y,
                     fmaf(wb.x, hv.z, fmaf(wb.y, hv.w, acc[b]))));
          }
        }
        *(float4*)&gacc[r * NB_B] = make_float4(acc[0], acc[1], acc[2], acc[3]);
      }
      __syncthreads();                 // gacc ready; hbuf reads done; poll done

      // update -> h0[t] (LDS + ring publish) ; feat[t+1]
      {
        float gi = gacc[(u)       * NB_B + bp];
        float gf = gacc[(128 + u) * NB_B + bp];
        float gg = gacc[(256 + u) * NB_B + bp];
        float go = gacc[(384 + u) * NB_B + bp];
        float cc = sig1(gf) * c0 + sig1(gi) * tanh1(gg);
        c0 = cc;
        float hv = sig1(go) * tanh1(cc);
        hbuf[bp * 320 + 64 + u] = hv;
        astoref(out + rbase(sl) + p * 512 + tid, hv);
      }
      if (bf < NB_B && t + 1 < SEQ) {
        const float* x = xptr + (size_t)(t + 1) * 5;
        float s = b1r;
        s = fmaf(w1r[0], x[0], s); s = fmaf(w1r[1], x[1], s);
        s = fmaf(w1r[2], x[2], s); s = fmaf(w1r[3], x[3], s);
        s = fmaf(w1r[4], x[4], s);
        hbuf[bf * 320 + m] = fmaxf(s, 0.0f);
      }
      __syncthreads();                 // ring stores drained (vmcnt0) + LDS ready
      if (tid == 0) astoreu(flag0, (unsigned)(t + 1));
      if (++sl == 3) sl = 0;
    }
  } else {
    // ---------------- layer-1 consumer ----------------
    const float bias1 = bih1[r] + bhh1[r];
    const uint2* wih1 = (const uint2*)(wt16 + WT1IH) + r;
    const uint2* whh1 = (const uint2*)(wt16 + WT1HH) + r;

    // prologue: stage h0[0]
    {
      unsigned f0 = aloadu(flag0);
      while (f0 < 1u) { __builtin_amdgcn_s_sleep(2); f0 = aloadu(flag0); }
      hbuf[bp * 320 + 64 + u] = aloadf(out + RINGA + p * 512 + tid);
    }
    __syncthreads();

    float c1 = 0.0f;
    int sl = 1;                        // slot(s+1)
    unsigned f0s = 0;                  // cached flag0 (monotonic)
    for (int s = 0; s < SEQ; ++s) {
      // prefetch h0[s+1] into a register; latency hidden under gates
      float rv = 0.0f;
      const bool pf = (s + 1 < SEQ);
      if (pf) {
        const unsigned tgt = (unsigned)(s + 2);
        while (f0s < tgt) {            // all threads (each guards its own load)
          f0s = aloadu(flag0);
          if (f0s < tgt) __builtin_amdgcn_s_sleep(2);
        }
        rv = aloadf(out + rbase(sl) + p * 512 + tid);
      }

      {  // layer1 gate rows: Wih1.h0[s] + Whh1.h1[s-1]   (r14-proven loop)
        float acc[NB_B];
        #pragma unroll
        for (int b = 0; b < NB_B; ++b) acc[b] = bias1;
        #pragma unroll 4
        for (int kc = 0; kc < 32; ++kc) {
          uint2 wp = wih1[kc * 512];
          WCVT(wp, wa, wb)
          #pragma unroll
          for (int b = 0; b < NB_B; ++b) {
            float4 hv = *(const float4*)&hbuf[b * 320 + 64 + kc * 4];
            acc[b] = fmaf(wa.x, hv.x, fmaf(wa.y, hv.y,
                     fmaf(wb.x, hv.z, fmaf(wb.y, hv.w, acc[b]))));
          }
        }
        #pragma unroll 4
        for (int kc = 0; kc < 32; ++kc) {
          uint2 wp = whh1[kc * 512];
          WCVT(wp, wa, wb)
          #pragma unroll
          for (int b = 0; b < NB_B; ++b) {
            float4 hv = *(const float4*)&hbuf[b * 320 + 192 + kc * 4];
            acc[b] = fmaf(wa.x, hv.x, fmaf(wa.y, hv.y,
                     fmaf(wb.x, hv.z, fmaf(wb.y, hv.w, acc[b]))));
          }
        }
        *(float4*)&gacc[r * NB_B] = make_float4(acc[0], acc[1], acc[2], acc[3]);
      }
      __syncthreads();                 // gacc ready; hbuf reads done; rv arrived

      {  // update -> h1[s]; stash at end; stage h0[s+1] from register
        float gi = gacc[(u)       * NB_B + bp];
        float gf = gacc[(128 + u) * NB_B + bp];
        float gg = gacc[(256 + u) * NB_B + bp];
        float go = gacc[(384 + u) * NB_B + bp];
        float cc = sig1(gf) * c1 + sig1(gi) * tanh1(gg);
        c1 = cc;
        float hvv = sig1(go) * tanh1(cc);
        hbuf[bp * 320 + 192 + u] = hvv;
        if (s == SEQ - 1)
          out[(size_t)(96 + p) * SLICE + 1024 + bp * 128 + u] = hvv;
      }
      if (pf) hbuf[bp * 320 + 64 + u] = rv;
      __syncthreads();                 // LDS consistent for next iter
      if (tid == 0) astoreu(flagC, (unsigned)(s + 2));   // slots <= s+1 consumed
      if (++sl == 3) sl = 0;
    }
  }
}

// base[b][m] = b1[m] + W1[m,0:128].hL[b] + W1[m,128:256].hR[b] -> out[b*SLICE + m]
extern "C" __global__ void __launch_bounds__(128)
mlp2_pre(const float* __restrict__ W1, const float* __restrict__ b1, float* out) {
  __shared__ float inpS[256];
  const int b = blockIdx.x, tid = threadIdx.x;
  inpS[tid]       = out[(size_t)(96  + (b >> 2)) * SLICE + 1024 + (b & 3) * 128 + tid];
  inpS[128 + tid] = out[(size_t)(160 + (b >> 2)) * SLICE + 1024 + (b & 3) * 128 + tid];
  __syncthreads();
  const float* wr = W1 + (size_t)tid * 257;
  float s = b1[tid];
  #pragma unroll 4
  for (int k = 0; k < 256; ++k) s = fmaf(wr[k], inpS[k], s);
  out[(size_t)b * SLICE + tid] = s;
}

// out[b][t][o] = b2[o] + sum_m W2[o][m] * relu(base[b][m] + W1[m][256]*T[b][t])
extern "C" __global__ void __launch_bounds__(256)
mlp2_k(const float* __restrict__ T, const float* __restrict__ W1,
       const float* __restrict__ b2, const float* __restrict__ W2, float* out) {
  __shared__ float baseS[128], w1l[128], w2S[384];
  const int b = blockIdx.x, tid = threadIdx.x;
  if (tid < 128) {
    baseS[tid] = out[(size_t)b * SLICE + tid];   // read own slice BEFORE any write
    w1l[tid]   = W1[(size_t)tid * 257 + 256];
  }
  w2S[tid] = W2[tid];                            // 256 threads fill all 384
  if (tid < 128) w2S[256 + tid] = W2[256 + tid];
  __syncthreads();
  float x[4];
  #pragma unroll
  for (int q = 0; q < 4; ++q) x[q] = T[(size_t)b * TLEN + tid + q * 256];
  float a0[4], a1[4], a2[4];
  #pragma unroll
  for (int q = 0; q < 4; ++q) { a0[q] = b2[0]; a1[q] = b2[1]; a2[q] = b2[2]; }
  for (int mm = 0; mm < 128; ++mm) {
    float bm = baseS[mm], wl = w1l[mm];
    float w20 = w2S[mm], w21 = w2S[128 + mm], w22 = w2S[256 + mm];
    #pragma unroll
    for (int q = 0; q < 4; ++q) {
      float hv = fmaxf(fmaf(wl, x[q], bm), 0.0f);
      a0[q] = fmaf(w20, hv, a0[q]);
      a1[q] = fmaf(w21, hv, a1[q]);
      a2[q] = fmaf(w22, hv, a2[q]);
    }
  }
  #pragma unroll
  for (int q = 0; q < 4; ++q) {
    float* o = out + ((size_t)b * TLEN + tid + q * 256) * 3;
    o[0] = a0[q]; o[1] = a1[q]; o[2] = a2[q];
  }
}

extern "C" void kernel_launch(void* const* d_in, const int* in_sizes, int n_in,
                              void* d_out, int out_size, void* d_ws, size_t ws_size,
                              hipStream_t stream) {
  (void)in_sizes; (void)n_in; (void)out_size; (void)d_ws; (void)ws_size;
  const float* X1   = (const float*)d_in[0];
  const float* X2   = (const float*)d_in[1];
  const float* T    = (const float*)d_in[2];
  const float* W1m  = (const float*)d_in[3];
  const float* b1m  = (const float*)d_in[4];
  const float* Wih0 = (const float*)d_in[5];
  const float* Whh0 = (const float*)d_in[6];
  const float* bih0 = (const float*)d_in[7];
  const float* bhh0 = (const float*)d_in[8];
  const float* Wih1 = (const float*)d_in[9];
  const float* Whh1 = (const float*)d_in[10];
  const float* bih1 = (const float*)d_in[11];
  const float* bhh1 = (const float*)d_in[12];
  const float* W1p  = (const float*)d_in[13];
  const float* b1p  = (const float*)d_in[14];
  const float* W2p  = (const float*)d_in[15];
  const float* b2p  = (const float*)d_in[16];

  float* out = (float*)d_out;

  // flags must start at 0 every call
  hipMemsetAsync((char*)d_out + (size_t)FLAGF * 4, 0, 65536, stream);

  prep_t<<<dim3(896), dim3(256), 0, stream>>>(Wih0, Whh0, Wih1, Whh1, (__half*)out);
  lstm_pair<<<dim3(256), dim3(NTHR), 0, stream>>>(X1, X2, W1m, b1m,
                                                  bih0, bhh0, bih1, bhh1, out, out);
  mlp2_pre<<<dim3(256), dim3(128), 0, stream>>>(W1p, b1p, out);
  mlp2_k<<<dim3(256), dim3(256), 0, stream>>>(T, W1p, b2p, W2p, out);
}